// Round 1
// baseline (15.321 us; speedup 1.0000x reference)
//
#include <hip/hip_runtime.h>

#define N_QUERIES 2097152
#define N_GRID 8
#define K_SITES 64

// 4 queries per thread: float4-vectorized load (2x) and store (3x).
__global__ __launch_bounds__(256) void voronoi_kernel(
    const float* __restrict__ x,
    const float* __restrict__ p,
    float* __restrict__ out)
{
    __shared__ float sp[K_SITES * 5];
    const int tid = threadIdx.x;
    for (int i = tid; i < K_SITES * 5; i += 256) sp[i] = p[i];
    __syncthreads();

    const int t = blockIdx.x * 256 + tid;   // one thread = 4 queries

    const float4* __restrict__ x4 = (const float4*)x;
    float4 a = x4[2 * t];       // q0.x q0.y q1.x q1.y
    float4 b = x4[2 * t + 1];   // q2.x q2.y q3.x q3.y

    float qx[4] = {a.x, a.z, b.x, b.z};
    float qy[4] = {a.y, a.w, b.y, b.w};
    float rc[4], gc[4], bc[4];

    #pragma unroll
    for (int q = 0; q < 4; ++q) {
        // nearest 2x2 cell-center block; clamp to grid
        float fx = qx[q] * (float)N_GRID - 0.5f;
        float fy = qy[q] * (float)N_GRID - 0.5f;
        int i0 = (int)floorf(fx); i0 = min(max(i0, 0), N_GRID - 2);
        int j0 = (int)floorf(fy); j0 = min(max(j0, 0), N_GRID - 2);

        float best = 1e30f;
        int bk = 0;
        // ascending k order + strict '<' matches numpy argmin tie-break
        #pragma unroll
        for (int di = 0; di < 2; ++di) {
            #pragma unroll
            for (int dj = 0; dj < 2; ++dj) {
                int k = (i0 + di) * N_GRID + (j0 + dj);
                float px = sp[k * 5 + 0];
                float py = sp[k * 5 + 1];
                float dx = qx[q] - px;
                float dy = qy[q] - py;
                // match numpy: round each product, then round the sum (no FMA)
                float d2 = __fadd_rn(__fmul_rn(dx, dx), __fmul_rn(dy, dy));
                if (d2 < best) { best = d2; bk = k; }
            }
        }
        rc[q] = sp[bk * 5 + 2];
        gc[q] = sp[bk * 5 + 3];
        bc[q] = sp[bk * 5 + 4];
    }

    float4* __restrict__ o4 = (float4*)out;
    o4[3 * t + 0] = make_float4(rc[0], gc[0], bc[0], rc[1]);
    o4[3 * t + 1] = make_float4(gc[1], bc[1], rc[2], gc[2]);
    o4[3 * t + 2] = make_float4(bc[2], rc[3], gc[3], bc[3]);
}

extern "C" void kernel_launch(void* const* d_in, const int* in_sizes, int n_in,
                              void* d_out, int out_size, void* d_ws, size_t ws_size,
                              hipStream_t stream) {
    const float* x = (const float*)d_in[0];
    const float* p = (const float*)d_in[1];
    float* out = (float*)d_out;

    const int threads_total = N_QUERIES / 4;      // 524288 threads
    const int block = 256;
    const int grid = threads_total / block;       // 2048 blocks

    voronoi_kernel<<<grid, block, 0, stream>>>(x, p, out);
}

// Round 2
// 15.252 us; speedup vs baseline: 1.0045x; 1.0045x over previous
//
#include <hip/hip_runtime.h>

#define N_QUERIES 2097152

// One thread = 4 queries. LDS holds row-adjacent position PAIRS (float4) and
// padded colors (float4) so each query costs 3x ds_read_b128 instead of 11x
// ds_read_b32.
__global__ __launch_bounds__(256) void voronoi_kernel(
    const float* __restrict__ x,
    const float* __restrict__ p,
    float* __restrict__ out)
{
    __shared__ float4 pairs[64]; // pairs[i*8+j] = {x(i,j), y(i,j), x(i,j+1), y(i,j+1)}
    __shared__ float4 cols[64];  // {r,g,b,0}

    const int tid = threadIdx.x;
    if (tid < 64) {
        int nb = ((tid & 7) == 7) ? tid : tid + 1;   // j+1 neighbor (j=7 unused)
        pairs[tid] = make_float4(p[tid * 5 + 0], p[tid * 5 + 1],
                                 p[nb * 5 + 0],  p[nb * 5 + 1]);
        cols[tid]  = make_float4(p[tid * 5 + 2], p[tid * 5 + 3],
                                 p[tid * 5 + 4], 0.0f);
    }
    __syncthreads();

    const int t = blockIdx.x * 256 + tid;

    const float4* __restrict__ x4 = (const float4*)x;
    float4 a = x4[2 * t];       // q0.x q0.y q1.x q1.y
    float4 b = x4[2 * t + 1];   // q2.x q2.y q3.x q3.y

    float qx[4] = {a.x, a.z, b.x, b.z};
    float qy[4] = {a.y, a.w, b.y, b.w};
    float4 c[4];

    #pragma unroll
    for (int q = 0; q < 4; ++q) {
        // nearest 2x2 cell-center block; geometric margin proof guarantees the
        // true argmin over all 64 jittered sites lies in this block.
        float fx = qx[q] * 8.0f - 0.5f;
        float fy = qy[q] * 8.0f - 0.5f;
        float fi = fminf(fmaxf(floorf(fx), 0.0f), 6.0f);
        float fj = fminf(fmaxf(floorf(fy), 0.0f), 6.0f);
        int k0 = (int)fi * 8 + (int)fj;

        float4 r0 = pairs[k0];       // sites k0, k0+1
        float4 r1 = pairs[k0 + 8];   // sites k0+8, k0+9

        // ascending k + strict '<' == np.argmin first-min tie-break;
        // __fmul_rn/__fadd_rn match numpy's separate roundings (no FMA).
        float dx, dy, d2, best;
        int bk = k0;
        dx = qx[q] - r0.x; dy = qy[q] - r0.y;
        best = __fadd_rn(__fmul_rn(dx, dx), __fmul_rn(dy, dy));
        dx = qx[q] - r0.z; dy = qy[q] - r0.w;
        d2 = __fadd_rn(__fmul_rn(dx, dx), __fmul_rn(dy, dy));
        if (d2 < best) { best = d2; bk = k0 + 1; }
        dx = qx[q] - r1.x; dy = qy[q] - r1.y;
        d2 = __fadd_rn(__fmul_rn(dx, dx), __fmul_rn(dy, dy));
        if (d2 < best) { best = d2; bk = k0 + 8; }
        dx = qx[q] - r1.z; dy = qy[q] - r1.w;
        d2 = __fadd_rn(__fmul_rn(dx, dx), __fmul_rn(dy, dy));
        if (d2 < best) { best = d2; bk = k0 + 9; }

        c[q] = cols[bk];
    }

    float4* __restrict__ o4 = (float4*)out;
    o4[3 * t + 0] = make_float4(c[0].x, c[0].y, c[0].z, c[1].x);
    o4[3 * t + 1] = make_float4(c[1].y, c[1].z, c[2].x, c[2].y);
    o4[3 * t + 2] = make_float4(c[2].z, c[3].x, c[3].y, c[3].z);
}

extern "C" void kernel_launch(void* const* d_in, const int* in_sizes, int n_in,
                              void* d_out, int out_size, void* d_ws, size_t ws_size,
                              hipStream_t stream) {
    const float* x = (const float*)d_in[0];
    const float* p = (const float*)d_in[1];
    float* out = (float*)d_out;

    const int threads_total = N_QUERIES / 4;  // 524288
    const int block = 256;
    const int grid = threads_total / block;   // 2048 blocks -> 8/CU, 32 waves/CU

    voronoi_kernel<<<grid, block, 0, stream>>>(x, p, out);
}

// Round 3
// 12.634 us; speedup vs baseline: 1.2127x; 1.2073x over previous
//
#include <hip/hip_runtime.h>

#define N_QUERIES 2097152

// Block = 256 threads, 1024 queries. All global loads/stores are unit-stride
// (lane-consecutive float4). Thread t owns queries {2t,2t+1,512+2t,512+2t+1}
// of its block; output is staged in LDS and stored coalesced.
__device__ __forceinline__ float4 nearest_col(float qx, float qy,
                                              const float4* __restrict__ pairs,
                                              const float4* __restrict__ cols)
{
    // nearest 2x2 cell-center block; jitter margin (0.1179 vs 0.0955) proves
    // the global argmin over all 64 sites lies in this block.
    float fx = qx * 8.0f - 0.5f;
    float fy = qy * 8.0f - 0.5f;
    float fi = fminf(fmaxf(floorf(fx), 0.0f), 6.0f);
    float fj = fminf(fmaxf(floorf(fy), 0.0f), 6.0f);
    int k0 = (int)fi * 8 + (int)fj;

    float4 r0 = pairs[k0];       // sites k0, k0+1
    float4 r1 = pairs[k0 + 8];   // sites k0+8, k0+9

    // ascending k + strict '<' == np.argmin tie-break;
    // __fmul_rn/__fadd_rn match numpy's separate roundings (no FMA).
    float dx, dy, d2, best;
    int bk = k0;
    dx = qx - r0.x; dy = qy - r0.y;
    best = __fadd_rn(__fmul_rn(dx, dx), __fmul_rn(dy, dy));
    dx = qx - r0.z; dy = qy - r0.w;
    d2 = __fadd_rn(__fmul_rn(dx, dx), __fmul_rn(dy, dy));
    if (d2 < best) { best = d2; bk = k0 + 1; }
    dx = qx - r1.x; dy = qy - r1.y;
    d2 = __fadd_rn(__fmul_rn(dx, dx), __fmul_rn(dy, dy));
    if (d2 < best) { best = d2; bk = k0 + 8; }
    dx = qx - r1.z; dy = qy - r1.w;
    d2 = __fadd_rn(__fmul_rn(dx, dx), __fmul_rn(dy, dy));
    if (d2 < best) { best = d2; bk = k0 + 9; }

    return cols[bk];
}

__global__ __launch_bounds__(256) void voronoi_kernel(
    const float* __restrict__ x,
    const float* __restrict__ p,
    float* __restrict__ out)
{
    __shared__ float4 pairs[64]; // pairs[i*8+j] = {x(i,j), y(i,j), x(i,j+1), y(i,j+1)}
    __shared__ float4 cols[64];  // {r,g,b,0}
    __shared__ float  oc[3072];  // 12 KB output staging (1024 queries x 3)

    const int tid = threadIdx.x;
    if (tid < 64) {
        int nb = ((tid & 7) == 7) ? tid : tid + 1;
        pairs[tid] = make_float4(p[tid * 5 + 0], p[tid * 5 + 1],
                                 p[nb * 5 + 0],  p[nb * 5 + 1]);
        cols[tid]  = make_float4(p[tid * 5 + 2], p[tid * 5 + 3],
                                 p[tid * 5 + 4], 0.0f);
    }
    __syncthreads();

    // coalesced loads: lane-consecutive float4
    const float4* __restrict__ x4 = (const float4*)x + (size_t)blockIdx.x * 512;
    float4 a = x4[tid];         // queries 2t, 2t+1   (block-relative)
    float4 b = x4[256 + tid];   // queries 512+2t, 512+2t+1

    float4 c0 = nearest_col(a.x, a.y, pairs, cols);
    float4 c1 = nearest_col(a.z, a.w, pairs, cols);
    float4 c2 = nearest_col(b.x, b.y, pairs, cols);
    float4 c3 = nearest_col(b.z, b.w, pairs, cols);

    // stage output tile in LDS (8B-aligned pairs -> ds_write_b64)
    float* o0 = &oc[6 * tid];          // queries 2t, 2t+1 -> floats [6t,6t+6)
    o0[0] = c0.x; o0[1] = c0.y; o0[2] = c0.z;
    o0[3] = c1.x; o0[4] = c1.y; o0[5] = c1.z;
    float* o1 = &oc[1536 + 6 * tid];   // queries 512+2t, 512+2t+1
    o1[0] = c2.x; o1[1] = c2.y; o1[2] = c2.z;
    o1[3] = c3.x; o1[4] = c3.y; o1[5] = c3.z;
    __syncthreads();

    // coalesced stores: lane-consecutive float4
    float4* __restrict__ o4 = (float4*)out + (size_t)blockIdx.x * 768;
    const float4* __restrict__ ocv = (const float4*)oc;
    o4[tid]       = ocv[tid];
    o4[256 + tid] = ocv[256 + tid];
    o4[512 + tid] = ocv[512 + tid];
}

extern "C" void kernel_launch(void* const* d_in, const int* in_sizes, int n_in,
                              void* d_out, int out_size, void* d_ws, size_t ws_size,
                              hipStream_t stream) {
    const float* x = (const float*)d_in[0];
    const float* p = (const float*)d_in[1];
    float* out = (float*)d_out;

    const int block = 256;
    const int grid = N_QUERIES / 1024;   // 2048 blocks
    voronoi_kernel<<<grid, block, 0, stream>>>(x, p, out);
}